// Round 1
// baseline (1198.460 us; speedup 1.0000x reference)
//
#include <hip/hip_runtime.h>
#include <math.h>

// Shapes (fixed by the problem)
#define NBATCH 128
#define NPTS   196     // 14*14 patches
#define DIN    768     // 3*16*16
#define DM     384
#define KCL    16
#define NEXP   8
#define NITER  10
#define NCLS   1000

// ---------------------------------------------------------------------------
// K0: init out = cb (classifier bias), zero the merge mask
// ---------------------------------------------------------------------------
__global__ __launch_bounds__(256) void init_kernel(const float* __restrict__ cb,
                                                   float* __restrict__ out,
                                                   int* __restrict__ mask) {
    int idx = blockIdx.x * 256 + threadIdx.x;
    if (idx < NBATCH * NCLS) {
        out[idx] = cb[idx % NCLS];
    } else if (idx < NBATCH * NCLS + 256) {
        mask[idx - NBATCH * NCLS] = 0;
    }
}

// ---------------------------------------------------------------------------
// K1: patch extraction + GEMM (25088x768 @ 768x384) + bias + LayerNorm + pnsq
// One block = 32 rows (patches) x all 384 cols. 256 threads, micro 4x12.
// LDS: As 32x32 (k-major) + Ws 32x384 = 52KB.
// ---------------------------------------------------------------------------
__global__ __launch_bounds__(256) void patch_ln_kernel(
        const float* __restrict__ x, const float* __restrict__ pw,
        const float* __restrict__ pb, const float* __restrict__ lng,
        const float* __restrict__ lnb, float* __restrict__ pn,
        float* __restrict__ pnsq) {
    __shared__ float As[32 * 32];    // [kk][row]
    __shared__ float Ws[32 * DM];    // [kk][col]
    const int tid  = threadIdx.x;
    const int m0   = blockIdx.x * 32;
    const int arow = tid >> 3, akg = tid & 7;
    const int m    = m0 + arow;
    const int bi   = m / NPTS, n = m - bi * NPTS;
    const int nh   = n / 14, nwp = n - nh * 14;
    const float* xb = x + (size_t)bi * 150528 + (size_t)(nh * 16) * 224 + nwp * 16;
    const int rg = tid >> 5, cg = tid & 31;   // 8 row-groups x 32 col-groups

    float acc[4][12];
#pragma unroll
    for (int r = 0; r < 4; ++r)
#pragma unroll
        for (int j = 0; j < 12; ++j) acc[r][j] = 0.f;

    const float4* pw4 = (const float4*)pw;
    for (int kci = 0; kci < 24; ++kci) {
        // stage A (gathered patch pixels), transposed to [kk][row]
        {
            int k = kci * 32 + akg * 4;
            int c = k >> 8, py = (k >> 4) & 15, px = k & 15;
            float4 xv = *(const float4*)(xb + c * 50176 + py * 224 + px);
            As[(akg * 4 + 0) * 32 + arow] = xv.x;
            As[(akg * 4 + 1) * 32 + arow] = xv.y;
            As[(akg * 4 + 2) * 32 + arow] = xv.z;
            As[(akg * 4 + 3) * 32 + arow] = xv.w;
        }
        // stage W (pw rows are contiguous -> straight float4 copy)
#pragma unroll
        for (int t = 0; t < 12; ++t) {
            int s = tid + t * 256;
            ((float4*)Ws)[s] = pw4[kci * 3072 + s];
        }
        __syncthreads();
#pragma unroll 8
        for (int kk = 0; kk < 32; ++kk) {
            float4 a = *(const float4*)&As[kk * 32 + rg * 4];
            float w[12];
            *(float4*)&w[0] = *(const float4*)&Ws[kk * DM + cg * 12];
            *(float4*)&w[4] = *(const float4*)&Ws[kk * DM + cg * 12 + 4];
            *(float4*)&w[8] = *(const float4*)&Ws[kk * DM + cg * 12 + 8];
            float ar[4] = {a.x, a.y, a.z, a.w};
#pragma unroll
            for (int r = 0; r < 4; ++r)
#pragma unroll
                for (int j = 0; j < 12; ++j) acc[r][j] += ar[r] * w[j];
        }
        __syncthreads();
    }

    // epilogue: +bias, LayerNorm (two-pass), write pn and pnsq
    float gvv[12], bvv[12], pbv[12];
#pragma unroll
    for (int j4 = 0; j4 < 3; ++j4) {
        *(float4*)&pbv[j4 * 4] = *(const float4*)(pb + cg * 12 + j4 * 4);
        *(float4*)&gvv[j4 * 4] = *(const float4*)(lng + cg * 12 + j4 * 4);
        *(float4*)&bvv[j4 * 4] = *(const float4*)(lnb + cg * 12 + j4 * 4);
    }
#pragma unroll
    for (int r = 0; r < 4; ++r) {
        float vloc[12];
        float s = 0.f;
#pragma unroll
        for (int j = 0; j < 12; ++j) { vloc[j] = acc[r][j] + pbv[j]; s += vloc[j]; }
#pragma unroll
        for (int off = 16; off >= 1; off >>= 1) s += __shfl_xor(s, off);
        float mu = s * (1.0f / DM);
        float q = 0.f;
#pragma unroll
        for (int j = 0; j < 12; ++j) { float dd = vloc[j] - mu; q += dd * dd; }
#pragma unroll
        for (int off = 16; off >= 1; off >>= 1) q += __shfl_xor(q, off);
        float rstd = rsqrtf(q * (1.0f / DM) + 1e-5f);
        float ov[12];
        float ssq = 0.f;
#pragma unroll
        for (int j = 0; j < 12; ++j) {
            float p = (vloc[j] - mu) * rstd * gvv[j] + bvv[j];
            ov[j] = p; ssq += p * p;
        }
#pragma unroll
        for (int off = 16; off >= 1; off >>= 1) ssq += __shfl_xor(ssq, off);
        int mr = m0 + rg * 4 + r;
        float* dst = pn + (size_t)mr * DM + cg * 12;
        *(float4*)(dst)     = *(float4*)&ov[0];
        *(float4*)(dst + 4) = *(float4*)&ov[4];
        *(float4*)(dst + 8) = *(float4*)&ov[8];
        if (cg == 0) pnsq[mr] = ssq;
    }
}

// ---------------------------------------------------------------------------
// K2: k-means (10 iters) per batch. Block = 1 batch, 256 threads.
// centers in LDS (padded rows); one point per lane for assignment.
// Output: clusters0 = centers + pos
// ---------------------------------------------------------------------------
__global__ __launch_bounds__(256) void kmeans_kernel(
        const float* __restrict__ pn, const float* __restrict__ pnsq,
        const float* __restrict__ pos, float* __restrict__ c0) {
    __shared__ float cent[KCL * 388];
    __shared__ float sums[KCL * DM];
    __shared__ float csq[KCL];
    __shared__ int   cnt[KCL];
    __shared__ int   asn[200];
    const int b = blockIdx.x;
    const int tid = threadIdx.x;
    const float* pnb = pn + (size_t)b * NPTS * DM;

    // init centers = pn[13*k]
    for (int idx = tid; idx < KCL * DM; idx += 256) {
        int k = idx / DM, d = idx - k * DM;
        cent[k * 388 + d] = pnb[(size_t)(13 * k) * DM + d];
    }
    __syncthreads();
    {   // csq
        int k = tid >> 4, s = tid & 15;
        float ss = 0.f;
        for (int t = 0; t < 24; ++t) { float v = cent[k * 388 + s + 16 * t]; ss += v * v; }
#pragma unroll
        for (int off = 8; off >= 1; off >>= 1) ss += __shfl_xor(ss, off);
        if (s == 0) csq[k] = ss;
    }
    __syncthreads();

    const int n   = tid;
    const int ncl = (n < NPTS) ? n : 0;
    const float4* prow = (const float4*)(pnb + (size_t)ncl * DM);
    const float mypnsq = pnsq[b * NPTS + ncl];

    for (int it = 0; it < NITER; ++it) {
        for (int idx = tid; idx < KCL * DM; idx += 256) sums[idx] = 0.f;
        if (tid < KCL) cnt[tid] = 0;
        __syncthreads();

        // ---- assignment ----
        float acc[KCL];
#pragma unroll
        for (int k = 0; k < KCL; ++k) acc[k] = 0.f;
        for (int d4 = 0; d4 < DM / 4; ++d4) {
            float4 p = prow[d4];
#pragma unroll
            for (int k = 0; k < KCL; ++k) {
                const float4 c = *(const float4*)&cent[k * 388 + d4 * 4];
                acc[k] += p.x * c.x + p.y * c.y + p.z * c.z + p.w * c.w;
            }
        }
        if (n < NPTS) {
            float best = (mypnsq - 2.0f * acc[0]) + csq[0];
            int bk = 0;
#pragma unroll
            for (int k = 1; k < KCL; ++k) {
                float v = (mypnsq - 2.0f * acc[k]) + csq[k];
                if (v < best) { best = v; bk = k; }   // strict < keeps first min
            }
            asn[n] = bk;
            atomicAdd(&cnt[bk], 1);
        }
        __syncthreads();

        // ---- accumulate sums: threads 0..191 each own 2 columns ----
        if (tid < 192) {
            const int c2i = 2 * tid;
            for (int nn = 0; nn < NPTS; ++nn) {
                int a = asn[nn];
                const float2 v = *(const float2*)(pnb + (size_t)nn * DM + c2i);
                float* s = &sums[a * DM + c2i];
                s[0] += v.x; s[1] += v.y;
            }
        }
        __syncthreads();

        // ---- new centers ----
        for (int idx = tid; idx < KCL * DM; idx += 256) {
            int k = idx / DM, d = idx - k * DM;
            int c = cnt[k];
            float old = cent[k * 388 + d];
            cent[k * 388 + d] = (c > 0) ? (sums[idx] / (float)c) : old;
        }
        __syncthreads();
        {   // csq
            int k = tid >> 4, s = tid & 15;
            float ss = 0.f;
            for (int t = 0; t < 24; ++t) { float v = cent[k * 388 + s + 16 * t]; ss += v * v; }
#pragma unroll
            for (int off = 8; off >= 1; off >>= 1) ss += __shfl_xor(ss, off);
            if (s == 0) csq[k] = ss;
        }
        __syncthreads();
    }

    // clusters0 = centers + pos
    for (int idx = tid; idx < KCL * DM; idx += 256) {
        int k = idx / DM, d = idx - k * DM;
        c0[(size_t)b * KCL * DM + idx] = cent[k * 388 + d] + pos[idx];
    }
}

// ---------------------------------------------------------------------------
// Generic fp32 GEMM: out(MxN) = A(MxK) @ W(KxN) + bias, optional exact GELU.
// BM=32, BN=128, BK=32, 256 threads, micro 4x4. Dims must be multiples.
// ---------------------------------------------------------------------------
template <int ACT>
__global__ __launch_bounds__(256) void gemm_kernel(
        const float* __restrict__ A, const float* __restrict__ W,
        const float* __restrict__ bias, float* __restrict__ out,
        int M, int N, int Kd) {
    __shared__ float As[32 * 32];
    __shared__ float Ws[32 * 128];
    const int n0 = blockIdx.x * 128;
    const int m0 = blockIdx.y * 32;
    const int tid = threadIdx.x;
    const int rg = tid >> 5, cg = tid & 31;
    const int arow = tid >> 3, akg = tid & 7;
    float acc[4][4];
#pragma unroll
    for (int r = 0; r < 4; ++r)
#pragma unroll
        for (int j = 0; j < 4; ++j) acc[r][j] = 0.f;

    for (int kc = 0; kc < Kd; kc += 32) {
        float4 av = *(const float4*)(A + (size_t)(m0 + arow) * Kd + kc + akg * 4);
        As[(akg * 4 + 0) * 32 + arow] = av.x;
        As[(akg * 4 + 1) * 32 + arow] = av.y;
        As[(akg * 4 + 2) * 32 + arow] = av.z;
        As[(akg * 4 + 3) * 32 + arow] = av.w;
#pragma unroll
        for (int t = 0; t < 4; ++t) {
            int s = tid + t * 256;
            int kk = s >> 5, c4i = s & 31;
            *(float4*)&Ws[kk * 128 + c4i * 4] =
                *(const float4*)(W + (size_t)(kc + kk) * N + n0 + c4i * 4);
        }
        __syncthreads();
#pragma unroll 16
        for (int kk = 0; kk < 32; ++kk) {
            float4 a = *(const float4*)&As[kk * 32 + rg * 4];
            float4 w = *(const float4*)&Ws[kk * 128 + cg * 4];
            float ar[4] = {a.x, a.y, a.z, a.w};
            float wr[4] = {w.x, w.y, w.z, w.w};
#pragma unroll
            for (int r = 0; r < 4; ++r)
#pragma unroll
                for (int j = 0; j < 4; ++j) acc[r][j] += ar[r] * wr[j];
        }
        __syncthreads();
    }
    float4 bv = *(const float4*)(bias + n0 + cg * 4);
    float bvr[4] = {bv.x, bv.y, bv.z, bv.w};
#pragma unroll
    for (int r = 0; r < 4; ++r) {
        float o[4];
#pragma unroll
        for (int j = 0; j < 4; ++j) {
            float v = acc[r][j] + bvr[j];
            if (ACT == 1) v = 0.5f * v * (1.0f + erff(v * 0.70710678118654752440f));
            o[j] = v;
        }
        *(float4*)(out + (size_t)(m0 + rg * 4 + r) * N + n0 + cg * 4) = *(float4*)&o[0];
    }
}

// ---------------------------------------------------------------------------
// K4: attention + expert softmax + spectral (L @ clusters). Block = 1 batch.
// ---------------------------------------------------------------------------
__global__ __launch_bounds__(256) void attn_spectral_kernel(
        const float* __restrict__ Qg, const float* __restrict__ Kg,
        const float* __restrict__ Vg, const float* __restrict__ ew,
        const float* __restrict__ eb, float* __restrict__ c2) {
    __shared__ float Qs[KCL * 388];   // Q, later C1
    __shared__ float Ks[KCL * 388];   // K, later V
    __shared__ float Ss[KCL * 17];
    __shared__ float hws[KCL * 9];
    __shared__ float rds[NEXP];
    __shared__ float Ls[NEXP * NEXP];
    const int b = blockIdx.x, tid = threadIdx.x;
    for (int idx = tid; idx < KCL * DM; idx += 256) {
        int i = idx / DM, d = idx - i * DM;
        size_t g = (size_t)b * KCL * DM + idx;
        Qs[i * 388 + d] = Qg[g];
        Ks[i * 388 + d] = Kg[g];
    }
    __syncthreads();
    {   // S = Q K^T / sqrt(D), softmax rows
        int i = tid >> 4, j = tid & 15;
        float acc = 0.f;
        for (int d = 0; d < DM; d += 4) {
            float4 q = *(const float4*)&Qs[i * 388 + d];
            float4 k = *(const float4*)&Ks[j * 388 + d];
            acc += q.x * k.x + q.y * k.y + q.z * k.z + q.w * k.w;
        }
        float s = acc / sqrtf((float)DM);
        float mx = s;
#pragma unroll
        for (int off = 8; off >= 1; off >>= 1) mx = fmaxf(mx, __shfl_xor(mx, off));
        float p = expf(s - mx);
        float sm = p;
#pragma unroll
        for (int off = 8; off >= 1; off >>= 1) sm += __shfl_xor(sm, off);
        Ss[i * 17 + j] = p / sm;
    }
    __syncthreads();
    // reload V into Ks
    for (int idx = tid; idx < KCL * DM; idx += 256) {
        int i = idx / DM, d = idx - i * DM;
        Ks[i * 388 + d] = Vg[(size_t)b * KCL * DM + idx];
    }
    __syncthreads();
    // C1 = attn @ V -> Qs
    for (int idx = tid; idx < KCL * DM; idx += 256) {
        int i = idx / DM, d = idx - i * DM;
        float acc = 0.f;
#pragma unroll
        for (int j = 0; j < KCL; ++j) acc += Ss[i * 17 + j] * Ks[j * 388 + d];
        Qs[i * 388 + d] = acc;
    }
    __syncthreads();
    // hw = softmax(C1 @ ew + eb, axis over K)
    if (tid < 128) {
        int e = tid >> 4, i = tid & 15;
        float l = 0.f;
        for (int d = 0; d < DM; ++d) l += Qs[i * 388 + d] * ew[d * NEXP + e];
        l += eb[e];
        float mx = l;
#pragma unroll
        for (int off = 8; off >= 1; off >>= 1) mx = fmaxf(mx, __shfl_xor(mx, off));
        float p = expf(l - mx);
        float sm = p;
#pragma unroll
        for (int off = 8; off >= 1; off >>= 1) sm += __shfl_xor(sm, off);
        float h = p / sm;
        hws[i * 9 + e] = h;
        float sd = h;
#pragma unroll
        for (int off = 8; off >= 1; off >>= 1) sd += __shfl_xor(sd, off);
        if (i == 0) rds[e] = 1.0f / sqrtf(sd);
    }
    __syncthreads();
    if (tid < 64) {   // L = I - rd[e] * (Hw^T Hw)
        int e = tid >> 3, f = tid & 7;
        float gsum = 0.f;
#pragma unroll
        for (int k = 0; k < KCL; ++k) gsum += hws[k * 9 + e] * hws[k * 9 + f];
        Ls[e * 8 + f] = ((e == f) ? 1.0f : 0.0f) - rds[e] * gsum;
    }
    __syncthreads();
    // c2 = pad(L) @ C1  (rows >= 8 become zero)
    for (int idx = tid; idx < KCL * DM; idx += 256) {
        int i = idx / DM, d = idx - i * DM;
        float acc = 0.f;
        if (i < NEXP) {
#pragma unroll
            for (int j = 0; j < NEXP; ++j) acc += Ls[i * 8 + j] * Qs[j * 388 + d];
        }
        c2[(size_t)b * KCL * DM + idx] = acc;
    }
}

// ---------------------------------------------------------------------------
// K6: normalize rows, sim = nc @ nc^T, OR (sim>0.9) into global mask
// ---------------------------------------------------------------------------
__global__ __launch_bounds__(256) void simmask_kernel(const float* __restrict__ c4,
                                                      int* __restrict__ mask) {
    __shared__ float Cs[KCL * 388];
    __shared__ float rns[KCL];
    const int b = blockIdx.x, tid = threadIdx.x;
    for (int idx = tid; idx < KCL * DM; idx += 256) {
        int i = idx / DM, d = idx - i * DM;
        Cs[i * 388 + d] = c4[(size_t)b * KCL * DM + idx];
    }
    __syncthreads();
    {
        int i = tid >> 4, s = tid & 15;
        float ss = 0.f;
        for (int t = 0; t < 24; ++t) { float v = Cs[i * 388 + s + 16 * t]; ss += v * v; }
#pragma unroll
        for (int off = 8; off >= 1; off >>= 1) ss += __shfl_xor(ss, off);
        if (s == 0) rns[i] = 1.0f / fmaxf(sqrtf(ss), 1e-12f);
    }
    __syncthreads();
    for (int idx = tid; idx < KCL * DM; idx += 256) {
        int i = idx / DM, d = idx - i * DM;
        Cs[i * 388 + d] *= rns[i];
    }
    __syncthreads();
    {
        int i = tid >> 4, j = tid & 15;
        if (j > i) {
            float dp = 0.f;
            for (int d = 0; d < DM; d += 4) {
                float4 a = *(const float4*)&Cs[i * 388 + d];
                float4 c = *(const float4*)&Cs[j * 388 + d];
                dp += a.x * c.x + a.y * c.y + a.z * c.z + a.w * c.w;
            }
            if (dp > 0.9f) atomicOr(&mask[i * KCL + j], 1);
        }
    }
}

// ---------------------------------------------------------------------------
// K7: sequential pairwise merge + mean + feedback gate -> c5
// threads 0..191 own 2 columns each; merge loop runs per-column in registers.
// ---------------------------------------------------------------------------
__global__ __launch_bounds__(256) void merge_fb_kernel(
        const float* __restrict__ c4, const int* __restrict__ mask,
        const float* __restrict__ fbw, const float* __restrict__ fbb,
        const float* __restrict__ fgw, const float* __restrict__ fgb,
        float* __restrict__ c5) {
    __shared__ int   mk[256];
    __shared__ float gs[DM];
    __shared__ float wred[3];
    __shared__ float gatev;
    const int b = blockIdx.x, tid = threadIdx.x;
    mk[tid] = mask[tid];
    const bool act = tid < 192;
    const int t = tid;
    float2 v[KCL];
    if (act) {
#pragma unroll
        for (int i = 0; i < KCL; ++i)
            v[i] = *(const float2*)(c4 + (size_t)b * KCL * DM + i * DM + 2 * t);
    }
    __syncthreads();
    if (act) {
#pragma unroll
        for (int i = 0; i < KCL; ++i)
#pragma unroll
            for (int j = i + 1; j < KCL; ++j)
                if (mk[i * KCL + j]) {
                    float mx = 0.5f * (v[i].x + v[j].x);
                    float my = 0.5f * (v[i].y + v[j].y);
                    v[i].x = mx; v[i].y = my; v[j].x = mx; v[j].y = my;
                }
    }
    float2 gv = {0.f, 0.f};
    if (act) {
#pragma unroll
        for (int i = 0; i < KCL; ++i) { gv.x += v[i].x; gv.y += v[i].y; }
        gv.x *= 0.0625f; gv.y *= 0.0625f;
        gs[2 * t] = gv.x; gs[2 * t + 1] = gv.y;
    }
    float pg = act ? (gv.x * fgw[2 * t] + gv.y * fgw[2 * t + 1]) : 0.f;
#pragma unroll
    for (int off = 32; off >= 1; off >>= 1) pg += __shfl_xor(pg, off);
    if (act && (tid & 63) == 0) wred[tid >> 6] = pg;
    __syncthreads();
    if (tid == 0) {
        float d = wred[0] + wred[1] + wred[2] + fgb[0];
        gatev = 1.0f / (1.0f + expf(-d));
    }
    __syncthreads();
    if (act) {
        float fx = fbb[2 * t], fy = fbb[2 * t + 1];
        for (int j = 0; j < DM; ++j) {
            float gj = gs[j];
            const float2 w = *(const float2*)(fbw + (size_t)j * DM + 2 * t);
            fx += gj * w.x; fy += gj * w.y;
        }
        float gt = gatev;
#pragma unroll
        for (int i = 0; i < KCL; ++i) {
            float2 o = {v[i].x + fx * gt, v[i].y + fy * gt};
            *(float2*)(c5 + (size_t)b * KCL * DM + i * DM + 2 * t) = o;
        }
    }
}

// ---------------------------------------------------------------------------
// K8: classifier, split-K with fp32 atomics. out pre-initialized with cb.
// grid (8 n-tiles, 4 m-tiles, 8 k-chunks of 768)
// ---------------------------------------------------------------------------
__global__ __launch_bounds__(256) void cls_kernel(const float* __restrict__ A,
                                                  const float* __restrict__ Wt,
                                                  float* __restrict__ out) {
    __shared__ float As[32 * 32];
    __shared__ float Ws[32 * 128];
    const int n0 = blockIdx.x * 128;
    const int m0 = blockIdx.y * 32;
    const int k0 = blockIdx.z * 768;
    const int tid = threadIdx.x;
    const int rg = tid >> 5, cg = tid & 31;
    const int arow = tid >> 3, akg = tid & 7;
    float acc[4][4];
#pragma unroll
    for (int r = 0; r < 4; ++r)
#pragma unroll
        for (int j = 0; j < 4; ++j) acc[r][j] = 0.f;

    for (int kc = k0; kc < k0 + 768; kc += 32) {
        float4 av = *(const float4*)(A + (size_t)(m0 + arow) * (KCL * DM) + kc + akg * 4);
        As[(akg * 4 + 0) * 32 + arow] = av.x;
        As[(akg * 4 + 1) * 32 + arow] = av.y;
        As[(akg * 4 + 2) * 32 + arow] = av.z;
        As[(akg * 4 + 3) * 32 + arow] = av.w;
#pragma unroll
        for (int ti = 0; ti < 4; ++ti) {
            int s = tid + ti * 256;
            int kk = s >> 5, c4i = s & 31;
            int col = n0 + c4i * 4;
            float4 wv = make_float4(0.f, 0.f, 0.f, 0.f);
            if (col < NCLS) wv = *(const float4*)(Wt + (size_t)(kc + kk) * NCLS + col);
            *(float4*)&Ws[kk * 128 + c4i * 4] = wv;
        }
        __syncthreads();
#pragma unroll 16
        for (int kk = 0; kk < 32; ++kk) {
            float4 a = *(const float4*)&As[kk * 32 + rg * 4];
            float4 w = *(const float4*)&Ws[kk * 128 + cg * 4];
            float ar[4] = {a.x, a.y, a.z, a.w};
            float wr[4] = {w.x, w.y, w.z, w.w};
#pragma unroll
            for (int r = 0; r < 4; ++r)
#pragma unroll
                for (int j = 0; j < 4; ++j) acc[r][j] += ar[r] * wr[j];
        }
        __syncthreads();
    }
    int col = n0 + cg * 4;
    if (col < NCLS) {
#pragma unroll
        for (int r = 0; r < 4; ++r) {
            int row = m0 + rg * 4 + r;
#pragma unroll
            for (int j = 0; j < 4; ++j)
                atomicAdd(&out[(size_t)row * NCLS + col + j], acc[r][j]);
        }
    }
}

// ---------------------------------------------------------------------------
extern "C" void kernel_launch(void* const* d_in, const int* in_sizes, int n_in,
                              void* d_out, int out_size, void* d_ws, size_t ws_size,
                              hipStream_t stream) {
    const float* x   = (const float*)d_in[0];
    const float* pw  = (const float*)d_in[1];
    const float* pb  = (const float*)d_in[2];
    const float* lng = (const float*)d_in[3];
    const float* lnb = (const float*)d_in[4];
    const float* pos = (const float*)d_in[5];
    const float* qw  = (const float*)d_in[6];
    const float* qb  = (const float*)d_in[7];
    const float* kw  = (const float*)d_in[8];
    const float* kb  = (const float*)d_in[9];
    const float* vw  = (const float*)d_in[10];
    const float* vb  = (const float*)d_in[11];
    const float* ew  = (const float*)d_in[12];
    const float* eb  = (const float*)d_in[13];
    const float* nw  = (const float*)d_in[14];
    const float* nb  = (const float*)d_in[15];
    const float* m1w = (const float*)d_in[16];
    const float* m1b = (const float*)d_in[17];
    const float* m2w = (const float*)d_in[18];
    const float* m2b = (const float*)d_in[19];
    const float* fbw = (const float*)d_in[20];
    const float* fbb = (const float*)d_in[21];
    const float* fgw = (const float*)d_in[22];
    const float* fgb = (const float*)d_in[23];
    const float* cw  = (const float*)d_in[24];
    const float* cb  = (const float*)d_in[25];
    float* out = (float*)d_out;
    float* ws  = (float*)d_ws;

    // workspace layout (floats)
    float* pn_   = ws;                    // 128*196*384 = 9,633,792
    float* pnsq_ = ws + 9633792;          // 25,088
    float* c0_   = ws + 9658880;          // 786,432 (clusters+pos; later c5)
    float* Q_    = ws + 10445312;         // 786,432 (later c3)
    float* K_    = ws + 11231744;         // 786,432 (later h)
    float* V_    = ws + 12018176;         // 786,432 (later c4)
    float* c2_   = ws + 12804608;         // 786,432
    int*   mask_ = (int*)(ws + 13591040); // 256 ints
    float* c3_ = Q_;
    float* h_  = K_;
    float* c4_ = V_;
    float* c5_ = c0_;

    init_kernel<<<501, 256, 0, stream>>>(cb, out, mask_);
    patch_ln_kernel<<<784, 256, 0, stream>>>(x, pw, pb, lng, lnb, pn_, pnsq_);
    kmeans_kernel<<<NBATCH, 256, 0, stream>>>(pn_, pnsq_, pos, c0_);
    gemm_kernel<0><<<dim3(3, 64), 256, 0, stream>>>(c0_, qw, qb, Q_, 2048, DM, DM);
    gemm_kernel<0><<<dim3(3, 64), 256, 0, stream>>>(c0_, kw, kb, K_, 2048, DM, DM);
    gemm_kernel<0><<<dim3(3, 64), 256, 0, stream>>>(c0_, vw, vb, V_, 2048, DM, DM);
    attn_spectral_kernel<<<NBATCH, 256, 0, stream>>>(Q_, K_, V_, ew, eb, c2_);
    gemm_kernel<0><<<dim3(3, 64), 256, 0, stream>>>(c2_, nw, nb, c3_, 2048, DM, DM);
    gemm_kernel<1><<<dim3(3, 64), 256, 0, stream>>>(c3_, m1w, m1b, h_, 2048, DM, DM);
    gemm_kernel<0><<<dim3(3, 64), 256, 0, stream>>>(h_, m2w, m2b, c4_, 2048, DM, DM);
    simmask_kernel<<<NBATCH, 256, 0, stream>>>(c4_, mask_);
    merge_fb_kernel<<<NBATCH, 256, 0, stream>>>(c4_, mask_, fbw, fbb, fgw, fgb, c5_);
    cls_kernel<<<dim3(8, 4, 8), 256, 0, stream>>>(c5_, cw, out);
}

// Round 2
// 1053.580 us; speedup vs baseline: 1.1375x; 1.1375x over previous
//
#include <hip/hip_runtime.h>
#include <math.h>

// Shapes (fixed by the problem)
#define NBATCH 128
#define NPTS   196     // 14*14 patches
#define DIN    768     // 3*16*16
#define DM     384
#define KCL    16
#define NEXP   8
#define NITER  10
#define NCLS   1000

// ---------------------------------------------------------------------------
// K0: init out = cb (classifier bias), zero the merge mask
// ---------------------------------------------------------------------------
__global__ __launch_bounds__(256) void init_kernel(const float* __restrict__ cb,
                                                   float* __restrict__ out,
                                                   int* __restrict__ mask) {
    int idx = blockIdx.x * 256 + threadIdx.x;
    if (idx < NBATCH * NCLS) {
        out[idx] = cb[idx % NCLS];
    } else if (idx < NBATCH * NCLS + 256) {
        mask[idx - NBATCH * NCLS] = 0;
    }
}

// ---------------------------------------------------------------------------
// K1: patch extraction + GEMM (25088x768 @ 768x384) + bias + LayerNorm + pnsq
// ---------------------------------------------------------------------------
__global__ __launch_bounds__(256) void patch_ln_kernel(
        const float* __restrict__ x, const float* __restrict__ pw,
        const float* __restrict__ pb, const float* __restrict__ lng,
        const float* __restrict__ lnb, float* __restrict__ pn,
        float* __restrict__ pnsq) {
    __shared__ float As[32 * 32];    // [kk][row]
    __shared__ float Ws[32 * DM];    // [kk][col]
    const int tid  = threadIdx.x;
    const int m0   = blockIdx.x * 32;
    const int arow = tid >> 3, akg = tid & 7;
    const int m    = m0 + arow;
    const int bi   = m / NPTS, n = m - bi * NPTS;
    const int nh   = n / 14, nwp = n - nh * 14;
    const float* xb = x + (size_t)bi * 150528 + (size_t)(nh * 16) * 224 + nwp * 16;
    const int rg = tid >> 5, cg = tid & 31;   // 8 row-groups x 32 col-groups

    float acc[4][12];
#pragma unroll
    for (int r = 0; r < 4; ++r)
#pragma unroll
        for (int j = 0; j < 12; ++j) acc[r][j] = 0.f;

    const float4* pw4 = (const float4*)pw;
    for (int kci = 0; kci < 24; ++kci) {
        {
            int k = kci * 32 + akg * 4;
            int c = k >> 8, py = (k >> 4) & 15, px = k & 15;
            float4 xv = *(const float4*)(xb + c * 50176 + py * 224 + px);
            As[(akg * 4 + 0) * 32 + arow] = xv.x;
            As[(akg * 4 + 1) * 32 + arow] = xv.y;
            As[(akg * 4 + 2) * 32 + arow] = xv.z;
            As[(akg * 4 + 3) * 32 + arow] = xv.w;
        }
#pragma unroll
        for (int t = 0; t < 12; ++t) {
            int s = tid + t * 256;
            ((float4*)Ws)[s] = pw4[kci * 3072 + s];
        }
        __syncthreads();
#pragma unroll 8
        for (int kk = 0; kk < 32; ++kk) {
            float4 a = *(const float4*)&As[kk * 32 + rg * 4];
            float w[12];
            *(float4*)&w[0] = *(const float4*)&Ws[kk * DM + cg * 12];
            *(float4*)&w[4] = *(const float4*)&Ws[kk * DM + cg * 12 + 4];
            *(float4*)&w[8] = *(const float4*)&Ws[kk * DM + cg * 12 + 8];
            float ar[4] = {a.x, a.y, a.z, a.w};
#pragma unroll
            for (int r = 0; r < 4; ++r)
#pragma unroll
                for (int j = 0; j < 12; ++j) acc[r][j] += ar[r] * w[j];
        }
        __syncthreads();
    }

    float gvv[12], bvv[12], pbv[12];
#pragma unroll
    for (int j4 = 0; j4 < 3; ++j4) {
        *(float4*)&pbv[j4 * 4] = *(const float4*)(pb + cg * 12 + j4 * 4);
        *(float4*)&gvv[j4 * 4] = *(const float4*)(lng + cg * 12 + j4 * 4);
        *(float4*)&bvv[j4 * 4] = *(const float4*)(lnb + cg * 12 + j4 * 4);
    }
#pragma unroll
    for (int r = 0; r < 4; ++r) {
        float vloc[12];
        float s = 0.f;
#pragma unroll
        for (int j = 0; j < 12; ++j) { vloc[j] = acc[r][j] + pbv[j]; s += vloc[j]; }
#pragma unroll
        for (int off = 16; off >= 1; off >>= 1) s += __shfl_xor(s, off);
        float mu = s * (1.0f / DM);
        float q = 0.f;
#pragma unroll
        for (int j = 0; j < 12; ++j) { float dd = vloc[j] - mu; q += dd * dd; }
#pragma unroll
        for (int off = 16; off >= 1; off >>= 1) q += __shfl_xor(q, off);
        float rstd = rsqrtf(q * (1.0f / DM) + 1e-5f);
        float ov[12];
        float ssq = 0.f;
#pragma unroll
        for (int j = 0; j < 12; ++j) {
            float p = (vloc[j] - mu) * rstd * gvv[j] + bvv[j];
            ov[j] = p; ssq += p * p;
        }
#pragma unroll
        for (int off = 16; off >= 1; off >>= 1) ssq += __shfl_xor(ssq, off);
        int mr = m0 + rg * 4 + r;
        float* dst = pn + (size_t)mr * DM + cg * 12;
        *(float4*)(dst)     = *(float4*)&ov[0];
        *(float4*)(dst + 4) = *(float4*)&ov[4];
        *(float4*)(dst + 8) = *(float4*)&ov[8];
        if (cg == 0) pnsq[mr] = ssq;
    }
}

// ---------------------------------------------------------------------------
// K2a: k-means init. centers = pn[13k], csq, cnt=0. One block per batch.
// ---------------------------------------------------------------------------
__global__ __launch_bounds__(256) void kmeans_init_kernel(
        const float* __restrict__ pn, float* __restrict__ cent,
        float* __restrict__ csq, int* __restrict__ cnt) {
    const int b = blockIdx.x, tid = threadIdx.x;
    const float* pnb = pn + (size_t)b * NPTS * DM;
    float* cb = cent + (size_t)b * KCL * DM;
    for (int i = tid; i < KCL * DM / 4; i += 256) {
        int k = i / (DM / 4), d4 = i - k * (DM / 4);
        ((float4*)cb)[i] = ((const float4*)(pnb + (size_t)(13 * k) * DM))[d4];
    }
    if (tid < 128) {   // csq from the source rows (identical values)
        int k = tid >> 3, sub = tid & 7;
        const float* row = pnb + (size_t)(13 * k) * DM + sub * 48;
        float ss = 0.f;
        for (int d = 0; d < 48; d += 4) {
            float4 v = *(const float4*)(row + d);
            ss += v.x * v.x + v.y * v.y + v.z * v.z + v.w * v.w;
        }
#pragma unroll
        for (int off = 4; off >= 1; off >>= 1) ss += __shfl_xor(ss, off);
        if (sub == 0) csq[b * KCL + k] = ss;
    }
    if (tid < KCL) cnt[b * KCL + tid] = 0;
}

// ---------------------------------------------------------------------------
// K2b: assignment. grid (7 tiles, 128 batches). 8 threads per point, each
// owning interleaved d4-chunks (bank-conflict-free broadcast LDS reads).
// ---------------------------------------------------------------------------
__global__ __launch_bounds__(256) void kmeans_assign_kernel(
        const float* __restrict__ pn, const float* __restrict__ pnsq,
        const float* __restrict__ cent, const float* __restrict__ csq,
        int* __restrict__ asn, int* __restrict__ cnt) {
    __shared__ float cs[KCL * DM];   // 24 KB
    __shared__ float cq[KCL];
    const int b = blockIdx.y, tile = blockIdx.x, tid = threadIdx.x;
    const float* cb = cent + (size_t)b * KCL * DM;
    for (int i = tid; i < KCL * DM / 4; i += 256)
        ((float4*)cs)[i] = ((const float4*)cb)[i];
    if (tid < KCL) cq[tid] = csq[b * KCL + tid];
    __syncthreads();

    const int p = tid >> 3, sub = tid & 7;
    const int n = tile * 32 + p;
    if (n >= NPTS) return;
    const float4* prow = (const float4*)(pn + ((size_t)b * NPTS + n) * DM);

    float acc[KCL];
#pragma unroll
    for (int k = 0; k < KCL; ++k) acc[k] = 0.f;
#pragma unroll 2
    for (int i = 0; i < 12; ++i) {
        const int d4 = sub + 8 * i;         // bank-quad = 4*sub: conflict-free
        float4 pv = prow[d4];
#pragma unroll
        for (int k = 0; k < KCL; ++k) {
            const float4 c = *(const float4*)&cs[k * DM + d4 * 4];
            acc[k] += pv.x * c.x + pv.y * c.y + pv.z * c.z + pv.w * c.w;
        }
    }
    // reduce over the 8 sub-lanes (consecutive lanes)
#pragma unroll
    for (int k = 0; k < KCL; ++k) {
        float a = acc[k];
        a += __shfl_xor(a, 1);
        a += __shfl_xor(a, 2);
        a += __shfl_xor(a, 4);
        acc[k] = a;
    }
    if (sub == 0) {
        const float mp = pnsq[b * NPTS + n];
        float best = (mp - 2.0f * acc[0]) + cq[0];
        int bk = 0;
#pragma unroll
        for (int k = 1; k < KCL; ++k) {
            float v = (mp - 2.0f * acc[k]) + cq[k];
            if (v < best) { best = v; bk = k; }   // strict < keeps first min
        }
        asn[b * NPTS + n] = bk;
        atomicAdd(&cnt[b * KCL + bk], 1);
    }
}

// ---------------------------------------------------------------------------
// K2c: centers update. grid (16 k, 128 batches). Ballot-compress matching
// points into wave masks, then each thread (float2 column) sums ~12 rows.
// Writes new center (in place), csq, and re-zeroes cnt for the next iter.
// ---------------------------------------------------------------------------
__global__ __launch_bounds__(256) void kmeans_update_kernel(
        const float* __restrict__ pn, const int* __restrict__ asn,
        int* __restrict__ cnt, float* __restrict__ cent,
        float* __restrict__ csq) {
    __shared__ unsigned long long msk[4];
    __shared__ float red[4];
    const int b = blockIdx.y, k = blockIdx.x, tid = threadIdx.x;

    int a = -1;
    if (tid < NPTS) a = asn[b * NPTS + tid];
    unsigned long long bal = __ballot(a == k);
    if ((tid & 63) == 0) msk[tid >> 6] = bal;
    __syncthreads();

    const int c = cnt[b * KCL + k];
    float sx = 0.f, sy = 0.f;
    const float* pnb = pn + (size_t)b * NPTS * DM + 2 * tid;
    if (tid < 192) {
#pragma unroll
        for (int w = 0; w < 4; ++w) {
            unsigned long long m = msk[w];
            while (m) {
                int nn = w * 64 + (int)__builtin_ctzll(m);
                m &= m - 1;
                float2 v = *(const float2*)(pnb + (size_t)nn * DM);
                sx += v.x; sy += v.y;
            }
        }
    }
    float* cr = cent + ((size_t)b * KCL + k) * DM + 2 * tid;
    float nx = 0.f, ny = 0.f;
    if (tid < 192) {
        if (c > 0) {
            float inv = 1.0f / (float)c;
            nx = sx * inv; ny = sy * inv;
        } else {
            nx = cr[0]; ny = cr[1];
        }
        cr[0] = nx; cr[1] = ny;
    }
    float ss = nx * nx + ny * ny;
#pragma unroll
    for (int off = 32; off >= 1; off >>= 1) ss += __shfl_xor(ss, off);
    if ((tid & 63) == 0) red[tid >> 6] = ss;
    __syncthreads();
    if (tid == 0) {
        csq[b * KCL + k] = red[0] + red[1] + red[2] + red[3];
        cnt[b * KCL + k] = 0;
    }
}

// ---------------------------------------------------------------------------
// K2d: finalize clusters0 = cent + pos (in place: cent aliases c0)
// ---------------------------------------------------------------------------
__global__ __launch_bounds__(256) void kmeans_finalize_kernel(
        float* __restrict__ cent, const float* __restrict__ pos) {
    int i = blockIdx.x * 256 + threadIdx.x;          // float4 index
    int within = i % (KCL * DM / 4);
    float4 cv = ((const float4*)cent)[i];
    float4 pv = ((const float4*)pos)[within];
    cv.x += pv.x; cv.y += pv.y; cv.z += pv.z; cv.w += pv.w;
    ((float4*)cent)[i] = cv;
}

// ---------------------------------------------------------------------------
// Generic fp32 GEMM: out(MxN) = A(MxK) @ W(KxN) + bias, optional exact GELU.
// ---------------------------------------------------------------------------
template <int ACT>
__global__ __launch_bounds__(256) void gemm_kernel(
        const float* __restrict__ A, const float* __restrict__ W,
        const float* __restrict__ bias, float* __restrict__ out,
        int M, int N, int Kd) {
    __shared__ float As[32 * 32];
    __shared__ float Ws[32 * 128];
    const int n0 = blockIdx.x * 128;
    const int m0 = blockIdx.y * 32;
    const int tid = threadIdx.x;
    const int rg = tid >> 5, cg = tid & 31;
    const int arow = tid >> 3, akg = tid & 7;
    float acc[4][4];
#pragma unroll
    for (int r = 0; r < 4; ++r)
#pragma unroll
        for (int j = 0; j < 4; ++j) acc[r][j] = 0.f;

    for (int kc = 0; kc < Kd; kc += 32) {
        float4 av = *(const float4*)(A + (size_t)(m0 + arow) * Kd + kc + akg * 4);
        As[(akg * 4 + 0) * 32 + arow] = av.x;
        As[(akg * 4 + 1) * 32 + arow] = av.y;
        As[(akg * 4 + 2) * 32 + arow] = av.z;
        As[(akg * 4 + 3) * 32 + arow] = av.w;
#pragma unroll
        for (int t = 0; t < 4; ++t) {
            int s = tid + t * 256;
            int kk = s >> 5, c4i = s & 31;
            *(float4*)&Ws[kk * 128 + c4i * 4] =
                *(const float4*)(W + (size_t)(kc + kk) * N + n0 + c4i * 4);
        }
        __syncthreads();
#pragma unroll 16
        for (int kk = 0; kk < 32; ++kk) {
            float4 a = *(const float4*)&As[kk * 32 + rg * 4];
            float4 w = *(const float4*)&Ws[kk * 128 + cg * 4];
            float ar[4] = {a.x, a.y, a.z, a.w};
            float wr[4] = {w.x, w.y, w.z, w.w};
#pragma unroll
            for (int r = 0; r < 4; ++r)
#pragma unroll
                for (int j = 0; j < 4; ++j) acc[r][j] += ar[r] * wr[j];
        }
        __syncthreads();
    }
    float4 bv = *(const float4*)(bias + n0 + cg * 4);
    float bvr[4] = {bv.x, bv.y, bv.z, bv.w};
#pragma unroll
    for (int r = 0; r < 4; ++r) {
        float o[4];
#pragma unroll
        for (int j = 0; j < 4; ++j) {
            float v = acc[r][j] + bvr[j];
            if (ACT == 1) v = 0.5f * v * (1.0f + erff(v * 0.70710678118654752440f));
            o[j] = v;
        }
        *(float4*)(out + (size_t)(m0 + rg * 4 + r) * N + n0 + cg * 4) = *(float4*)&o[0];
    }
}

// ---------------------------------------------------------------------------
// K4: attention + expert softmax + spectral (L @ clusters). Block = 1 batch.
// ---------------------------------------------------------------------------
__global__ __launch_bounds__(256) void attn_spectral_kernel(
        const float* __restrict__ Qg, const float* __restrict__ Kg,
        const float* __restrict__ Vg, const float* __restrict__ ew,
        const float* __restrict__ eb, float* __restrict__ c2) {
    __shared__ float Qs[KCL * 388];   // Q, later C1
    __shared__ float Ks[KCL * 388];   // K, later V
    __shared__ float Ss[KCL * 17];
    __shared__ float hws[KCL * 9];
    __shared__ float rds[NEXP];
    __shared__ float Ls[NEXP * NEXP];
    const int b = blockIdx.x, tid = threadIdx.x;
    for (int idx = tid; idx < KCL * DM; idx += 256) {
        int i = idx / DM, d = idx - i * DM;
        size_t g = (size_t)b * KCL * DM + idx;
        Qs[i * 388 + d] = Qg[g];
        Ks[i * 388 + d] = Kg[g];
    }
    __syncthreads();
    {   // S = Q K^T / sqrt(D), softmax rows
        int i = tid >> 4, j = tid & 15;
        float acc = 0.f;
        for (int d = 0; d < DM; d += 4) {
            float4 q = *(const float4*)&Qs[i * 388 + d];
            float4 k = *(const float4*)&Ks[j * 388 + d];
            acc += q.x * k.x + q.y * k.y + q.z * k.z + q.w * k.w;
        }
        float s = acc / sqrtf((float)DM);
        float mx = s;
#pragma unroll
        for (int off = 8; off >= 1; off >>= 1) mx = fmaxf(mx, __shfl_xor(mx, off));
        float p = expf(s - mx);
        float sm = p;
#pragma unroll
        for (int off = 8; off >= 1; off >>= 1) sm += __shfl_xor(sm, off);
        Ss[i * 17 + j] = p / sm;
    }
    __syncthreads();
    for (int idx = tid; idx < KCL * DM; idx += 256) {
        int i = idx / DM, d = idx - i * DM;
        Ks[i * 388 + d] = Vg[(size_t)b * KCL * DM + idx];
    }
    __syncthreads();
    for (int idx = tid; idx < KCL * DM; idx += 256) {
        int i = idx / DM, d = idx - i * DM;
        float acc = 0.f;
#pragma unroll
        for (int j = 0; j < KCL; ++j) acc += Ss[i * 17 + j] * Ks[j * 388 + d];
        Qs[i * 388 + d] = acc;
    }
    __syncthreads();
    if (tid < 128) {
        int e = tid >> 4, i = tid & 15;
        float l = 0.f;
        for (int d = 0; d < DM; ++d) l += Qs[i * 388 + d] * ew[d * NEXP + e];
        l += eb[e];
        float mx = l;
#pragma unroll
        for (int off = 8; off >= 1; off >>= 1) mx = fmaxf(mx, __shfl_xor(mx, off));
        float p = expf(l - mx);
        float sm = p;
#pragma unroll
        for (int off = 8; off >= 1; off >>= 1) sm += __shfl_xor(sm, off);
        float h = p / sm;
        hws[i * 9 + e] = h;
        float sd = h;
#pragma unroll
        for (int off = 8; off >= 1; off >>= 1) sd += __shfl_xor(sd, off);
        if (i == 0) rds[e] = 1.0f / sqrtf(sd);
    }
    __syncthreads();
    if (tid < 64) {
        int e = tid >> 3, f = tid & 7;
        float gsum = 0.f;
#pragma unroll
        for (int k = 0; k < KCL; ++k) gsum += hws[k * 9 + e] * hws[k * 9 + f];
        Ls[e * 8 + f] = ((e == f) ? 1.0f : 0.0f) - rds[e] * gsum;
    }
    __syncthreads();
    for (int idx = tid; idx < KCL * DM; idx += 256) {
        int i = idx / DM, d = idx - i * DM;
        float acc = 0.f;
        if (i < NEXP) {
#pragma unroll
            for (int j = 0; j < NEXP; ++j) acc += Ls[i * 8 + j] * Qs[j * 388 + d];
        }
        c2[(size_t)b * KCL * DM + idx] = acc;
    }
}

// ---------------------------------------------------------------------------
// K6: normalize rows, sim = nc @ nc^T, OR (sim>0.9) into global mask
// ---------------------------------------------------------------------------
__global__ __launch_bounds__(256) void simmask_kernel(const float* __restrict__ c4,
                                                      int* __restrict__ mask) {
    __shared__ float Cs[KCL * 388];
    __shared__ float rns[KCL];
    const int b = blockIdx.x, tid = threadIdx.x;
    for (int idx = tid; idx < KCL * DM; idx += 256) {
        int i = idx / DM, d = idx - i * DM;
        Cs[i * 388 + d] = c4[(size_t)b * KCL * DM + idx];
    }
    __syncthreads();
    {
        int i = tid >> 4, s = tid & 15;
        float ss = 0.f;
        for (int t = 0; t < 24; ++t) { float v = Cs[i * 388 + s + 16 * t]; ss += v * v; }
#pragma unroll
        for (int off = 8; off >= 1; off >>= 1) ss += __shfl_xor(ss, off);
        if (s == 0) rns[i] = 1.0f / fmaxf(sqrtf(ss), 1e-12f);
    }
    __syncthreads();
    for (int idx = tid; idx < KCL * DM; idx += 256) {
        int i = idx / DM, d = idx - i * DM;
        Cs[i * 388 + d] *= rns[i];
    }
    __syncthreads();
    {
        int i = tid >> 4, j = tid & 15;
        if (j > i) {
            float dp = 0.f;
            for (int d = 0; d < DM; d += 4) {
                float4 a = *(const float4*)&Cs[i * 388 + d];
                float4 c = *(const float4*)&Cs[j * 388 + d];
                dp += a.x * c.x + a.y * c.y + a.z * c.z + a.w * c.w;
            }
            if (dp > 0.9f) atomicOr(&mask[i * KCL + j], 1);
        }
    }
}

// ---------------------------------------------------------------------------
// K7: sequential pairwise merge + mean + feedback gate -> c5
// ---------------------------------------------------------------------------
__global__ __launch_bounds__(256) void merge_fb_kernel(
        const float* __restrict__ c4, const int* __restrict__ mask,
        const float* __restrict__ fbw, const float* __restrict__ fbb,
        const float* __restrict__ fgw, const float* __restrict__ fgb,
        float* __restrict__ c5) {
    __shared__ int   mk[256];
    __shared__ float gs[DM];
    __shared__ float wred[3];
    __shared__ float gatev;
    const int b = blockIdx.x, tid = threadIdx.x;
    mk[tid] = mask[tid];
    const bool act = tid < 192;
    const int t = tid;
    float2 v[KCL];
    if (act) {
#pragma unroll
        for (int i = 0; i < KCL; ++i)
            v[i] = *(const float2*)(c4 + (size_t)b * KCL * DM + i * DM + 2 * t);
    }
    __syncthreads();
    if (act) {
#pragma unroll
        for (int i = 0; i < KCL; ++i)
#pragma unroll
            for (int j = i + 1; j < KCL; ++j)
                if (mk[i * KCL + j]) {
                    float mx = 0.5f * (v[i].x + v[j].x);
                    float my = 0.5f * (v[i].y + v[j].y);
                    v[i].x = mx; v[i].y = my; v[j].x = mx; v[j].y = my;
                }
    }
    float2 gv = {0.f, 0.f};
    if (act) {
#pragma unroll
        for (int i = 0; i < KCL; ++i) { gv.x += v[i].x; gv.y += v[i].y; }
        gv.x *= 0.0625f; gv.y *= 0.0625f;
        gs[2 * t] = gv.x; gs[2 * t + 1] = gv.y;
    }
    float pg = act ? (gv.x * fgw[2 * t] + gv.y * fgw[2 * t + 1]) : 0.f;
#pragma unroll
    for (int off = 32; off >= 1; off >>= 1) pg += __shfl_xor(pg, off);
    if (act && (tid & 63) == 0) wred[tid >> 6] = pg;
    __syncthreads();
    if (tid == 0) {
        float d = wred[0] + wred[1] + wred[2] + fgb[0];
        gatev = 1.0f / (1.0f + expf(-d));
    }
    __syncthreads();
    if (act) {
        float fx = fbb[2 * t], fy = fbb[2 * t + 1];
        for (int j = 0; j < DM; ++j) {
            float gj = gs[j];
            const float2 w = *(const float2*)(fbw + (size_t)j * DM + 2 * t);
            fx += gj * w.x; fy += gj * w.y;
        }
        float gt = gatev;
#pragma unroll
        for (int i = 0; i < KCL; ++i) {
            float2 o = {v[i].x + fx * gt, v[i].y + fy * gt};
            *(float2*)(c5 + (size_t)b * KCL * DM + i * DM + 2 * t) = o;
        }
    }
}

// ---------------------------------------------------------------------------
// K8: classifier, split-K with fp32 atomics. out pre-initialized with cb.
// ---------------------------------------------------------------------------
__global__ __launch_bounds__(256) void cls_kernel(const float* __restrict__ A,
                                                  const float* __restrict__ Wt,
                                                  float* __restrict__ out) {
    __shared__ float As[32 * 32];
    __shared__ float Ws[32 * 128];
    const int n0 = blockIdx.x * 128;
    const int m0 = blockIdx.y * 32;
    const int k0 = blockIdx.z * 768;
    const int tid = threadIdx.x;
    const int rg = tid >> 5, cg = tid & 31;
    const int arow = tid >> 3, akg = tid & 7;
    float acc[4][4];
#pragma unroll
    for (int r = 0; r < 4; ++r)
#pragma unroll
        for (int j = 0; j < 4; ++j) acc[r][j] = 0.f;

    for (int kc = k0; kc < k0 + 768; kc += 32) {
        float4 av = *(const float4*)(A + (size_t)(m0 + arow) * (KCL * DM) + kc + akg * 4);
        As[(akg * 4 + 0) * 32 + arow] = av.x;
        As[(akg * 4 + 1) * 32 + arow] = av.y;
        As[(akg * 4 + 2) * 32 + arow] = av.z;
        As[(akg * 4 + 3) * 32 + arow] = av.w;
#pragma unroll
        for (int ti = 0; ti < 4; ++ti) {
            int s = tid + ti * 256;
            int kk = s >> 5, c4i = s & 31;
            int col = n0 + c4i * 4;
            float4 wv = make_float4(0.f, 0.f, 0.f, 0.f);
            if (col < NCLS) wv = *(const float4*)(Wt + (size_t)(kc + kk) * NCLS + col);
            *(float4*)&Ws[kk * 128 + c4i * 4] = wv;
        }
        __syncthreads();
#pragma unroll 16
        for (int kk = 0; kk < 32; ++kk) {
            float4 a = *(const float4*)&As[kk * 32 + rg * 4];
            float4 w = *(const float4*)&Ws[kk * 128 + cg * 4];
            float ar[4] = {a.x, a.y, a.z, a.w};
            float wr[4] = {w.x, w.y, w.z, w.w};
#pragma unroll
            for (int r = 0; r < 4; ++r)
#pragma unroll
                for (int j = 0; j < 4; ++j) acc[r][j] += ar[r] * wr[j];
        }
        __syncthreads();
    }
    int col = n0 + cg * 4;
    if (col < NCLS) {
#pragma unroll
        for (int r = 0; r < 4; ++r) {
            int row = m0 + rg * 4 + r;
#pragma unroll
            for (int j = 0; j < 4; ++j)
                atomicAdd(&out[(size_t)row * NCLS + col + j], acc[r][j]);
        }
    }
}

// ---------------------------------------------------------------------------
extern "C" void kernel_launch(void* const* d_in, const int* in_sizes, int n_in,
                              void* d_out, int out_size, void* d_ws, size_t ws_size,
                              hipStream_t stream) {
    const float* x   = (const float*)d_in[0];
    const float* pw  = (const float*)d_in[1];
    const float* pb  = (const float*)d_in[2];
    const float* lng = (const float*)d_in[3];
    const float* lnb = (const float*)d_in[4];
    const float* pos = (const float*)d_in[5];
    const float* qw  = (const float*)d_in[6];
    const float* qb  = (const float*)d_in[7];
    const float* kw  = (const float*)d_in[8];
    const float* kb  = (const float*)d_in[9];
    const float* vw  = (const float*)d_in[10];
    const float* vb  = (const float*)d_in[11];
    const float* ew  = (const float*)d_in[12];
    const float* eb  = (const float*)d_in[13];
    const float* nw  = (const float*)d_in[14];
    const float* nb  = (const float*)d_in[15];
    const float* m1w = (const float*)d_in[16];
    const float* m1b = (const float*)d_in[17];
    const float* m2w = (const float*)d_in[18];
    const float* m2b = (const float*)d_in[19];
    const float* fbw = (const float*)d_in[20];
    const float* fbb = (const float*)d_in[21];
    const float* fgw = (const float*)d_in[22];
    const float* fgb = (const float*)d_in[23];
    const float* cw  = (const float*)d_in[24];
    const float* cb  = (const float*)d_in[25];
    float* out = (float*)d_out;
    float* ws  = (float*)d_ws;

    // workspace layout (floats)
    float* pn_   = ws;                    // 128*196*384 = 9,633,792
    float* pnsq_ = ws + 9633792;          // 25,088
    float* c0_   = ws + 9658880;          // 786,432  (kmeans centers; then clusters0; later c5)
    float* Q_    = ws + 10445312;         // 786,432 (later c3)
    float* K_    = ws + 11231744;         // 786,432 (later h)
    float* V_    = ws + 12018176;         // 786,432 (later c4)
    float* c2_   = ws + 12804608;         // 786,432
    int*   mask_ = (int*)(ws + 13591040); // 256 ints
    float* csq_  = ws + 13591296;         // 2048
    int*   cnt_  = (int*)(ws + 13593344); // 2048 ints
    int*   asn_  = (int*)(ws + 13595392); // 25,088 ints
    float* cent_ = c0_;                   // centers evolve in place, become c0
    float* c3_ = Q_;
    float* h_  = K_;
    float* c4_ = V_;
    float* c5_ = c0_;

    init_kernel<<<501, 256, 0, stream>>>(cb, out, mask_);
    patch_ln_kernel<<<784, 256, 0, stream>>>(x, pw, pb, lng, lnb, pn_, pnsq_);

    kmeans_init_kernel<<<NBATCH, 256, 0, stream>>>(pn_, cent_, csq_, cnt_);
    for (int it = 0; it < NITER; ++it) {
        kmeans_assign_kernel<<<dim3(7, NBATCH), 256, 0, stream>>>(
            pn_, pnsq_, cent_, csq_, asn_, cnt_);
        kmeans_update_kernel<<<dim3(KCL, NBATCH), 256, 0, stream>>>(
            pn_, asn_, cnt_, cent_, csq_);
    }
    kmeans_finalize_kernel<<<768, 256, 0, stream>>>(cent_, pos);

    gemm_kernel<0><<<dim3(3, 64), 256, 0, stream>>>(c0_, qw, qb, Q_, 2048, DM, DM);
    gemm_kernel<0><<<dim3(3, 64), 256, 0, stream>>>(c0_, kw, kb, K_, 2048, DM, DM);
    gemm_kernel<0><<<dim3(3, 64), 256, 0, stream>>>(c0_, vw, vb, V_, 2048, DM, DM);
    attn_spectral_kernel<<<NBATCH, 256, 0, stream>>>(Q_, K_, V_, ew, eb, c2_);
    gemm_kernel<0><<<dim3(3, 64), 256, 0, stream>>>(c2_, nw, nb, c3_, 2048, DM, DM);
    gemm_kernel<1><<<dim3(3, 64), 256, 0, stream>>>(c3_, m1w, m1b, h_, 2048, DM, DM);
    gemm_kernel<0><<<dim3(3, 64), 256, 0, stream>>>(h_, m2w, m2b, c4_, 2048, DM, DM);
    simmask_kernel<<<NBATCH, 256, 0, stream>>>(c4_, mask_);
    merge_fb_kernel<<<NBATCH, 256, 0, stream>>>(c4_, mask_, fbw, fbb, fgw, fgb, c5_);
    cls_kernel<<<dim3(8, 4, 8), 256, 0, stream>>>(c5_, cw, out);
}